// Round 4
// baseline (10738.515 us; speedup 1.0000x reference)
//
#include <hip/hip_runtime.h>

#define NB 512
#define NL 512
#define NK 103
#define NH 512
#define NI 105
#define XROW (NL * NK)

typedef _Float16 half8 __attribute__((ext_vector_type(8)));
typedef _Float16 half4 __attribute__((ext_vector_type(4)));
typedef float floatx4 __attribute__((ext_vector_type(4)));

// LDS layout (bytes)
#define XB_STR 136   // halves; 68 dwords = 4 mod 32 banks -> conflict-light
#define B2_STR 136
#define YST_STR 72
#define Y2_STR 16
#define OFF_XB 0              // 2 x 64 x 136 halves = 34816 B
#define OFF_B2 34816          // 64 x 136 halves = 17408 B
#define OFF_YST 52224         // 64 x 72 halves = 9216 B
#define OFF_Y2 61440          // 64 x 16 halves = 2048 B
#define OFF_FR 63488          // 448 floats of space
#define SMEM_BYTES 65280      // <= 64 KiB: within default dynamic-LDS limit

#define SPIN_MAX (1 << 20)    // ~0.1s worst case; legit waits are microseconds

__device__ __forceinline__ float fast_sigmoid(float v) {
  v = fminf(fmaxf(v, -30.f), 30.f);
  return __builtin_amdgcn_rcpf(1.f + __expf(-v));
}
__device__ __forceinline__ float fast_tanh(float v) {
  v = fminf(fmaxf(v, -15.f), 15.f);
  float e = __expf(-2.f * v);
  return (1.f - e) * __builtin_amdgcn_rcpf(1.f + e);
}

__global__ void __launch_bounds__(256, 1)
lstm_persist(const float* __restrict__ x, const float* __restrict__ pos,
             const float* __restrict__ h0, const float* __restrict__ c0,
             const float* __restrict__ Wih, const float* __restrict__ Whh,
             const float* __restrict__ bih, const float* __restrict__ bhh,
             const float* __restrict__ W1, const float* __restrict__ b1,
             const float* __restrict__ W2, const float* __restrict__ b2,
             const float* __restrict__ W3, const float* __restrict__ b3,
             float* __restrict__ out, void* __restrict__ ws)
{
  extern __shared__ char smem[];
  _Float16* XB  = (_Float16*)(smem + OFF_XB);
  _Float16* B2s = (_Float16*)(smem + OFF_B2);
  _Float16* YST = (_Float16*)(smem + OFF_YST);
  _Float16* Y2  = (_Float16*)(smem + OFF_Y2);
  float* FR  = (float*)(smem + OFF_FR);
  float* b1s = FR;          // 64
  float* b2s = FR + 64;     // 16
  float* w3s = FR + 80;     // 32
  float* b3s = FR + 112;    // 2
  float* wy0 = FR + 114;    // 64
  float* wy1 = FR + 178;    // 64
  float* bgs = FR + 242;    // 64
  float* ypres = FR + 306;  // 128
  volatile int* abflag = (volatile int*)(FR + 440);

  const int tid = threadIdx.x;
  const int g  = blockIdx.x >> 5;   // batch group: rows 64g..64g+63
  const int cs = blockIdx.x & 31;   // h-column slice: 16cs..16cs+15
  const int w  = tid >> 6, l = tid & 63;
  const int c16 = l & 15, q = l >> 4;
  const int rh = w >> 1;            // row half (32 rows)
  const int ch = w & 1;             // 0 = gates, 1 = MLP(W1)

  unsigned* flags = (unsigned*)ws;                 // [8][32] spaced 4 dwords
  _Float16* hbuf = (_Float16*)((char*)ws + 4096);  // 2 x slice-major [32][512][16] f16
  const int HBUF = NB * NH;

  if (tid == 0) *abflag = 0;
  // ---- zero xbuf (incl. zero-pad cols 103..127) ----
  {
    unsigned* xz = (unsigned*)XB;
    for (int i = tid; i < 8704; i += 256) xz[i] = 0;
  }
  // ---- stage W_ih x-part into LDS fp16 (64 gate cols for this slice) ----
  for (int idx = tid; idx < 64 * 128; idx += 256) {
    int cc = idx >> 7, k = idx & 127;
    int gr = (cc >> 4) * NH + cs * 16 + (cc & 15);
    float v = (k < NK) ? Wih[(size_t)gr * NI + k] : 0.f;
    B2s[cc * B2_STR + k] = (_Float16)v;
  }
  // ---- small fp32 tables ----
  if (tid < 64) {
    int gr = (tid >> 4) * NH + cs * 16 + (tid & 15);
    wy0[tid] = Wih[(size_t)gr * NI + 103];
    wy1[tid] = Wih[(size_t)gr * NI + 104];
    bgs[tid] = bih[gr] + bhh[gr];
    b1s[tid] = b1[tid];
  }
  if (tid < 16) b2s[tid] = b2[tid];
  if (tid < 32) w3s[tid] = W3[tid];
  if (tid < 2)  b3s[tid] = b3[tid];

  // ---- h0 -> hbuf[0], slice-major ----
  for (int idx = tid; idx < 1024; idx += 256) {
    int r = idx >> 4, c = idx & 15;
    hbuf[(size_t)cs * 8192 + (size_t)(64 * g + r) * 16 + c] =
        (_Float16)h0[(size_t)(64 * g + r) * NH + cs * 16 + c];
  }

  // ---- B weight fragments -> registers (held for all 512 steps) ----
  half8 bfr[4][16];
  #pragma unroll
  for (int ct = 0; ct < 4; ++ct) {
    const int rown = ch ? (ct * 16 + c16) : (ct * NH + cs * 16 + c16);
    const float* rp = (ch ? W1 : Whh) + (size_t)rown * NH;
    #pragma unroll
    for (int kk = 0; kk < 16; ++kk) {
      const float* p = rp + kk * 32 + q * 8;
      floatx4 f0 = *(const floatx4*)(p);
      floatx4 f1 = *(const floatx4*)(p + 4);
      half8 hv;
      hv[0]=(_Float16)f0[0]; hv[1]=(_Float16)f0[1]; hv[2]=(_Float16)f0[2]; hv[3]=(_Float16)f0[3];
      hv[4]=(_Float16)f1[0]; hv[5]=(_Float16)f1[1]; hv[6]=(_Float16)f1[2]; hv[7]=(_Float16)f1[3];
      bfr[ct][kk] = hv;
    }
  }
  // W2 fragments (layer-2 MFMA B operand), W1 waves only
  half8 w2f[2];
  if (ch) {
    #pragma unroll
    for (int kk = 0; kk < 2; ++kk) {
      const float* p = W2 + c16 * 64 + kk * 32 + q * 8;
      floatx4 f0 = *(const floatx4*)(p);
      floatx4 f1 = *(const floatx4*)(p + 4);
      half8 hv;
      hv[0]=(_Float16)f0[0]; hv[1]=(_Float16)f0[1]; hv[2]=(_Float16)f0[2]; hv[3]=(_Float16)f0[3];
      hv[4]=(_Float16)f1[0]; hv[5]=(_Float16)f1[1]; hv[6]=(_Float16)f1[2]; hv[7]=(_Float16)f1[3];
      w2f[kk] = hv;
    }
  }
  // cell state (fp32, registers), gate waves
  float cacc[2][4];
  if (!ch) {
    #pragma unroll
    for (int rt = 0; rt < 2; ++rt)
      #pragma unroll
      for (int reg = 0; reg < 4; ++reg)
        cacc[rt][reg] = c0[(size_t)(64 * g + 32 * rh + 16 * rt + q * 4 + reg) * NH + cs * 16 + c16];
  }

  // coalesced x_t -> LDS f16 stager (gate waves; 2 lanes per row)
  auto xstage = [&](int t1) {
    _Float16* xb = XB + (size_t)(t1 & 1) * 64 * XB_STR;
    const int row = 32 * rh + (l >> 1);
    const int p = l & 1;
    const float* src = x + (size_t)(64 * g + row) * XROW + (size_t)t1 * NK + p * 52;
    _Float16* dst = xb + row * XB_STR + p * 52;
    const int nfull = p ? 12 : 13;
    for (int cnk = 0; cnk < nfull; ++cnk) {
      float f0 = src[cnk * 4 + 0], f1 = src[cnk * 4 + 1];
      float f2 = src[cnk * 4 + 2], f3 = src[cnk * 4 + 3];
      half4 hv; hv[0]=(_Float16)f0; hv[1]=(_Float16)f1; hv[2]=(_Float16)f2; hv[3]=(_Float16)f3;
      *(half4*)(dst + cnk * 4) = hv;
    }
    if (p) {  // elements 100..102 (103 never touched: avoids OOB at buffer end)
      dst[48] = (_Float16)src[48];
      dst[49] = (_Float16)src[49];
      dst[50] = (_Float16)src[50];
    }
  };

  unsigned ep = 1;
  auto gbar = [&](void) {  // 32-wg group barrier: flags + parallel poll + timeout escape
    __syncthreads();
    if (w == 0) {
      if (l == 0)
        __hip_atomic_store(flags + ((g << 5) + cs) * 4, ep, __ATOMIC_RELEASE, __HIP_MEMORY_SCOPE_AGENT);
      unsigned* f = flags + ((g << 5) + (l & 31)) * 4;
      int spins = 0;
      while (__hip_atomic_load(f, __ATOMIC_RELAXED, __HIP_MEMORY_SCOPE_AGENT) < ep) {
        __builtin_amdgcn_s_sleep(1);
        if (++spins > SPIN_MAX) { *abflag = 1; break; }  // hang-proof escape
      }
      __builtin_amdgcn_fence(__ATOMIC_ACQUIRE, "agent");
    }
    __syncthreads();
    ep++;
  };

  __syncthreads();          // xbuf zeroing + abflag init complete
  if (!ch) xstage(0);       // x_0 -> xbuf[0]
  gbar();                   // h0 + staging visible group-wide
  if (*abflag) return;

  // step t: all waves MFMA over h_{t-1}; W1 waves finish y_{t-1}=MLP(h_{t-1});
  // gate waves add x_t + y-feedback, update c, write h_t. t==NL: final y only.
  for (int t = 0; t <= NL; ++t) {
    const _Float16* hr = hbuf + (size_t)(t & 1) * HBUF;

    // ---- phase 1: K=512 over h_{t-1} (A from global slice-major, B from regs)
    // chunked (4 x 4) to cap live registers (no spill, no occupancy cliff)
    floatx4 acc[4][2] = {};
    const int growb = 64 * g + 32 * rh + c16;
    #pragma unroll
    for (int kc = 0; kc < 4; ++kc) {
      half8 ar[2][4];
      #pragma unroll
      for (int kk = 0; kk < 4; ++kk) {
        #pragma unroll
        for (int rt = 0; rt < 2; ++rt) {
          const _Float16* ap = hr + (size_t)((kc * 4 + kk) * 2 + (q >> 1)) * 8192
                               + (size_t)(growb + 16 * rt) * 16 + (q & 1) * 8;
          ar[rt][kk] = *(const half8*)ap;
        }
      }
      #pragma unroll
      for (int kk = 0; kk < 4; ++kk)
        #pragma unroll
        for (int ct = 0; ct < 4; ++ct)
          #pragma unroll
          for (int rt = 0; rt < 2; ++rt)
            acc[ct][rt] = __builtin_amdgcn_mfma_f32_16x16x32_f16(
                ar[rt][kk], bfr[ct][kc * 4 + kk], acc[ct][rt], 0, 0, 0);
    }

    // ---- phase 2 (gate waves): x_t contribution, K=128 from LDS ----
    if (!ch && t < NL) {
      const _Float16* xb = XB + (size_t)(t & 1) * 64 * XB_STR;
      #pragma unroll
      for (int kb = 0; kb < 4; ++kb) {
        half8 ax[2];
        #pragma unroll
        for (int rt = 0; rt < 2; ++rt)
          ax[rt] = *(const half8*)(xb + (32 * rh + 16 * rt + c16) * XB_STR + kb * 32 + q * 8);
        #pragma unroll
        for (int ct = 0; ct < 4; ++ct) {
          half8 bf = *(const half8*)(B2s + (ct * 16 + c16) * B2_STR + kb * 32 + q * 8);
          #pragma unroll
          for (int rt = 0; rt < 2; ++rt)
            acc[ct][rt] = __builtin_amdgcn_mfma_f32_16x16x32_f16(ax[rt], bf, acc[ct][rt], 0, 0, 0);
        }
      }
      if (t + 1 < NL) xstage(t + 1);  // prefetch x_{t+1} into other LDS buffer
    }

    // ---- W1 waves: y_{t-1} (or pos init at t==0) ----
    if (ch) {
      if (t == 0) {
        if (l < 32) {
          int row = 32 * rh + l;
          const float* pp = pos + (size_t)(64 * g + row) * (NL * 2);
          ypres[row * 2 + 0] = pp[0];
          ypres[row * 2 + 1] = pp[1];
        }
      } else {
        // layer1 relu -> YST (f16); each W1 wave touches only its own 32 rows
        #pragma unroll
        for (int ct = 0; ct < 4; ++ct)
          #pragma unroll
          for (int rt = 0; rt < 2; ++rt)
            #pragma unroll
            for (int reg = 0; reg < 4; ++reg) {
              int row = 32 * rh + 16 * rt + q * 4 + reg;
              float v = acc[ct][rt][reg] + b1s[ct * 16 + c16];
              YST[row * YST_STR + ct * 16 + c16] = (_Float16)fmaxf(v, 0.f);
            }
        // layer2 via MFMA (16 outs, K=64)
        floatx4 a2c[2] = {};
        #pragma unroll
        for (int kk2 = 0; kk2 < 2; ++kk2)
          #pragma unroll
          for (int rt = 0; rt < 2; ++rt) {
            half8 af = *(const half8*)(YST + (32 * rh + 16 * rt + c16) * YST_STR + kk2 * 32 + q * 8);
            a2c[rt] = __builtin_amdgcn_mfma_f32_16x16x32_f16(af, w2f[kk2], a2c[rt], 0, 0, 0);
          }
        // relu2 -> Y2
        #pragma unroll
        for (int rt = 0; rt < 2; ++rt)
          #pragma unroll
          for (int reg = 0; reg < 4; ++reg) {
            int row = 32 * rh + 16 * rt + q * 4 + reg;
            float v = a2c[rt][reg] + b2s[c16];
            Y2[row * Y2_STR + c16] = (_Float16)fmaxf(v, 0.f);
          }
        // layer3 (2 outs, K=16) + relu -> ypres (+ global pos out by cs==0)
        if (l < 32) {
          int row = 32 * rh + l;
          float y0 = b3s[0], y1 = b3s[1];
          #pragma unroll
          for (int k = 0; k < 16; ++k) {
            float vv = (float)Y2[row * Y2_STR + k];
            y0 += vv * w3s[k];
            y1 += vv * w3s[16 + k];
          }
          y0 = fmaxf(y0, 0.f); y1 = fmaxf(y1, 0.f);
          ypres[row * 2 + 0] = y0;
          ypres[row * 2 + 1] = y1;
          if (cs == 0) {
            float2* op = (float2*)(out + (size_t)(64 * g + row) * (NL * 2) + (size_t)(t - 1) * 2);
            *op = make_float2(y0, y1);
          }
        }
      }
    }
    __syncthreads();  // ypres ready for gate epilogue

    // ---- gate epilogue: feedback + bias + LSTM cell + h_t write ----
    if (!ch && t < NL) {
      _Float16* hw = hbuf + (size_t)((t + 1) & 1) * HBUF;
      #pragma unroll
      for (int rt = 0; rt < 2; ++rt)
        #pragma unroll
        for (int reg = 0; reg < 4; ++reg) {
          int rl = 32 * rh + 16 * rt + q * 4 + reg;
          float yp0 = ypres[rl * 2], yp1 = ypres[rl * 2 + 1];
          float gi = acc[0][rt][reg] + bgs[c16]      + yp0 * wy0[c16]      + yp1 * wy1[c16];
          float gf = acc[1][rt][reg] + bgs[16 + c16] + yp0 * wy0[16 + c16] + yp1 * wy1[16 + c16];
          float gg = acc[2][rt][reg] + bgs[32 + c16] + yp0 * wy0[32 + c16] + yp1 * wy1[32 + c16];
          float go = acc[3][rt][reg] + bgs[48 + c16] + yp0 * wy0[48 + c16] + yp1 * wy1[48 + c16];
          float iv = fast_sigmoid(gi);
          float fv = fast_sigmoid(gf);
          float gv = fast_tanh(gg);
          float ov = fast_sigmoid(go);
          float cn = fv * cacc[rt][reg] + iv * gv;
          cacc[rt][reg] = cn;
          float hn = ov * fast_tanh(cn);
          hw[(size_t)cs * 8192 + (size_t)(64 * g + rl) * 16 + c16] = (_Float16)hn;
          if (t == NL - 1) {
            out[(size_t)(NB * NL * 2) + (size_t)(64 * g + rl) * NH + cs * 16 + c16] = hn;
            out[(size_t)(NB * NL * 2) + (size_t)(NB * NH) + (size_t)(64 * g + rl) * NH + cs * 16 + c16] = cn;
          }
        }
    }

    if (t < NL) {
      gbar();  // publish h_t to the group
      if (*abflag) return;  // barrier timed out somewhere: terminate cleanly
    }
  }
}

extern "C" void kernel_launch(void* const* d_in, const int* in_sizes, int n_in,
                              void* d_out, int out_size, void* d_ws, size_t ws_size,
                              hipStream_t stream) {
  (void)in_sizes; (void)n_in; (void)out_size; (void)ws_size;
  const float* x   = (const float*)d_in[0];
  const float* pos = (const float*)d_in[1];
  const float* h0  = (const float*)d_in[2];
  const float* c0  = (const float*)d_in[3];
  const float* Wih = (const float*)d_in[4];
  const float* Whh = (const float*)d_in[5];
  const float* bih = (const float*)d_in[6];
  const float* bhh = (const float*)d_in[7];
  const float* W1  = (const float*)d_in[8];
  const float* b1  = (const float*)d_in[9];
  const float* W2  = (const float*)d_in[10];
  const float* b2  = (const float*)d_in[11];
  const float* W3  = (const float*)d_in[12];
  const float* b3  = (const float*)d_in[13];
  float* out = (float*)d_out;

  hipMemsetAsync(d_ws, 0, 4096, stream);  // barrier flags

  void* args[] = { (void*)&x, (void*)&pos, (void*)&h0, (void*)&c0,
                   (void*)&Wih, (void*)&Whh, (void*)&bih, (void*)&bhh,
                   (void*)&W1, (void*)&b1, (void*)&W2, (void*)&b2,
                   (void*)&W3, (void*)&b3, (void*)&out, (void*)&d_ws };

  // Primary: cooperative launch (proven to work in R1). If the runtime
  // rejects it (occupancy-validation boundary), fall back to a plain launch —
  // 256 blocks at 1 block/CU on 256 CUs are co-resident by capacity, which is
  // all the hand-rolled group barrier needs.
  hipError_t err = hipLaunchCooperativeKernel(
      reinterpret_cast<void*>(lstm_persist),
      dim3(256, 1, 1), dim3(256, 1, 1), args, (unsigned)SMEM_BYTES, stream);
  if (err != hipSuccess) {
    (void)hipGetLastError();  // clear sticky error
    lstm_persist<<<dim3(256, 1, 1), dim3(256, 1, 1), SMEM_BYTES, stream>>>(
        x, pos, h0, c0, Wih, Whh, bih, bhh, W1, b1, W2, b2, W3, b3, out, d_ws);
  }
}

// Round 5
// 6215.374 us; speedup vs baseline: 1.7277x; 1.7277x over previous
//
#include <hip/hip_runtime.h>

#define NB 512
#define NL 512
#define NK 103
#define NH 512
#define NI 105
#define XROW (NL * NK)

typedef _Float16 half8 __attribute__((ext_vector_type(8)));
typedef _Float16 half4 __attribute__((ext_vector_type(4)));
typedef float floatx4 __attribute__((ext_vector_type(4)));

// LDS layout (bytes)
#define XB_STR 136   // halves; 272B row stride (16B aligned), conflict-light
#define B2_STR 136
#define YST_STR 72
#define Y2_STR 16
#define OFF_XB 0              // 2 x 64 x 136 halves = 34816 B
#define OFF_B2 34816          // 64 x 136 halves = 17408 B
#define OFF_YST 52224         // 64 x 72 halves = 9216 B
#define OFF_Y2 61440          // 64 x 16 halves = 2048 B (aliased as HTX after mid-step sync)
#define OFF_FR 63488          // 448 floats of space
#define SMEM_BYTES 65280      // <= 64 KiB

#define SPIN_MAX (1 << 20)    // hang-proof escape; legit waits are microseconds

#define A_LOAD(p)  __hip_atomic_load((p),  __ATOMIC_RELAXED, __HIP_MEMORY_SCOPE_AGENT)
#define A_STORE(p, v) __hip_atomic_store((p), (v), __ATOMIC_RELAXED, __HIP_MEMORY_SCOPE_AGENT)

__device__ __forceinline__ float fast_sigmoid(float v) {
  v = fminf(fmaxf(v, -30.f), 30.f);
  return __builtin_amdgcn_rcpf(1.f + __expf(-v));
}
__device__ __forceinline__ float fast_tanh(float v) {
  v = fminf(fmaxf(v, -15.f), 15.f);
  float e = __expf(-2.f * v);
  return (1.f - e) * __builtin_amdgcn_rcpf(1.f + e);
}

__global__ void __launch_bounds__(256, 1)
lstm_persist(const float* __restrict__ x, const float* __restrict__ pos,
             const float* __restrict__ h0, const float* __restrict__ c0,
             const float* __restrict__ Wih, const float* __restrict__ Whh,
             const float* __restrict__ bih, const float* __restrict__ bhh,
             const float* __restrict__ W1, const float* __restrict__ b1,
             const float* __restrict__ W2, const float* __restrict__ b2,
             const float* __restrict__ W3, const float* __restrict__ b3,
             float* __restrict__ out, void* __restrict__ ws)
{
  extern __shared__ char smem[];
  _Float16* XB  = (_Float16*)(smem + OFF_XB);
  _Float16* B2s = (_Float16*)(smem + OFF_B2);
  _Float16* YST = (_Float16*)(smem + OFF_YST);
  _Float16* Y2  = (_Float16*)(smem + OFF_Y2);
  _Float16* HTX = Y2;   // reuse: Y2 use ends before mid-step sync, HTX starts after
  float* FR  = (float*)(smem + OFF_FR);
  float* b1s = FR;          // 64
  float* b2s = FR + 64;     // 16
  float* w3s = FR + 80;     // 32
  float* b3s = FR + 112;    // 2
  float* wy0 = FR + 114;    // 64
  float* wy1 = FR + 178;    // 64
  float* bgs = FR + 242;    // 64
  float* ypres = FR + 306;  // 128
  volatile int* abflag = (volatile int*)(FR + 440);

  const int tid = threadIdx.x;
  const int g  = blockIdx.x >> 5;   // batch group: rows 64g..64g+63
  const int cs = blockIdx.x & 31;   // h-column slice: 16cs..16cs+15
  const int w  = tid >> 6, l = tid & 63;
  const int c16 = l & 15, q = l >> 4;
  const int rh = w >> 1;            // row half (32 rows)
  const int ch = w & 1;             // 0 = gates, 1 = MLP(W1)

  unsigned* flags = (unsigned*)ws;                 // [8][32] spaced 4 dwords
  _Float16* hbuf = (_Float16*)((char*)ws + 4096);  // 2 x slice-major [32][512][16] f16
  const int HBUF = NB * NH;

  if (tid == 0) *abflag = 0;
  // ---- zero xbuf (incl. zero-pad cols 103..127) ----
  {
    unsigned* xz = (unsigned*)XB;
    for (int i = tid; i < 8704; i += 256) xz[i] = 0;
  }
  // ---- stage W_ih x-part into LDS fp16 (64 gate cols for this slice) ----
  for (int idx = tid; idx < 64 * 128; idx += 256) {
    int cc = idx >> 7, k = idx & 127;
    int gr = (cc >> 4) * NH + cs * 16 + (cc & 15);
    float v = (k < NK) ? Wih[(size_t)gr * NI + k] : 0.f;
    B2s[cc * B2_STR + k] = (_Float16)v;
  }
  // ---- small fp32 tables ----
  if (tid < 64) {
    int gr = (tid >> 4) * NH + cs * 16 + (tid & 15);
    wy0[tid] = Wih[(size_t)gr * NI + 103];
    wy1[tid] = Wih[(size_t)gr * NI + 104];
    bgs[tid] = bih[gr] + bhh[gr];
    b1s[tid] = b1[tid];
  }
  if (tid < 16) b2s[tid] = b2[tid];
  if (tid < 32) w3s[tid] = W3[tid];
  if (tid < 2)  b3s[tid] = b3[tid];

  // ---- h0 -> hbuf[0], slice-major, via relaxed agent (sc1) stores ----
  {
    int row = tid >> 2, cc = tid & 3;
    const float* src = h0 + (size_t)(64 * g + row) * NH + cs * 16 + cc * 4;
    union { unsigned long long u; half4 h; } cv;
    cv.h[0] = (_Float16)src[0]; cv.h[1] = (_Float16)src[1];
    cv.h[2] = (_Float16)src[2]; cv.h[3] = (_Float16)src[3];
    A_STORE((unsigned long long*)(hbuf + (size_t)cs * 8192 + (size_t)(64 * g + row) * 16 + cc * 4), cv.u);
  }

  // ---- B weight fragments -> registers (held for all 512 steps) ----
  half8 bfr[4][16];
  #pragma unroll
  for (int ct = 0; ct < 4; ++ct) {
    const int rown = ch ? (ct * 16 + c16) : (ct * NH + cs * 16 + c16);
    const float* rp = (ch ? W1 : Whh) + (size_t)rown * NH;
    #pragma unroll
    for (int kk = 0; kk < 16; ++kk) {
      const float* p = rp + kk * 32 + q * 8;
      floatx4 f0 = *(const floatx4*)(p);
      floatx4 f1 = *(const floatx4*)(p + 4);
      half8 hv;
      hv[0]=(_Float16)f0[0]; hv[1]=(_Float16)f0[1]; hv[2]=(_Float16)f0[2]; hv[3]=(_Float16)f0[3];
      hv[4]=(_Float16)f1[0]; hv[5]=(_Float16)f1[1]; hv[6]=(_Float16)f1[2]; hv[7]=(_Float16)f1[3];
      bfr[ct][kk] = hv;
    }
  }
  // W2 fragments (layer-2 MFMA B operand), W1 waves only
  half8 w2f[2];
  if (ch) {
    #pragma unroll
    for (int kk = 0; kk < 2; ++kk) {
      const float* p = W2 + c16 * 64 + kk * 32 + q * 8;
      floatx4 f0 = *(const floatx4*)(p);
      floatx4 f1 = *(const floatx4*)(p + 4);
      half8 hv;
      hv[0]=(_Float16)f0[0]; hv[1]=(_Float16)f0[1]; hv[2]=(_Float16)f0[2]; hv[3]=(_Float16)f0[3];
      hv[4]=(_Float16)f1[0]; hv[5]=(_Float16)f1[1]; hv[6]=(_Float16)f1[2]; hv[7]=(_Float16)f1[3];
      w2f[kk] = hv;
    }
  }
  // cell state (fp32, registers), gate waves
  float cacc[2][4];
  if (!ch) {
    #pragma unroll
    for (int rt = 0; rt < 2; ++rt)
      #pragma unroll
      for (int reg = 0; reg < 4; ++reg)
        cacc[rt][reg] = c0[(size_t)(64 * g + 32 * rh + 16 * rt + q * 4 + reg) * NH + cs * 16 + c16];
  }

  // coalesced x_t -> LDS f16 stager (gate waves; 2 lanes per row)
  auto xstage = [&](int t1) {
    _Float16* xb = XB + (size_t)(t1 & 1) * 64 * XB_STR;
    const int row = 32 * rh + (l >> 1);
    const int p = l & 1;
    const float* src = x + (size_t)(64 * g + row) * XROW + (size_t)t1 * NK + p * 52;
    _Float16* dst = xb + row * XB_STR + p * 52;
    const int nfull = p ? 12 : 13;
    for (int cnk = 0; cnk < nfull; ++cnk) {
      float f0 = src[cnk * 4 + 0], f1 = src[cnk * 4 + 1];
      float f2 = src[cnk * 4 + 2], f3 = src[cnk * 4 + 3];
      half4 hv; hv[0]=(_Float16)f0; hv[1]=(_Float16)f1; hv[2]=(_Float16)f2; hv[3]=(_Float16)f3;
      *(half4*)(dst + cnk * 4) = hv;
    }
    if (p) {  // elements 100..102 (103 never touched: avoids OOB at buffer end)
      dst[48] = (_Float16)src[48];
      dst[49] = (_Float16)src[49];
      dst[50] = (_Float16)src[50];
    }
  };

  unsigned ep = 1;
  // 32-wg group barrier, FENCELESS: __syncthreads drains vmcnt (sc1 stores
  // complete at IC) before the relaxed flag store; readers poll relaxed.
  // No buffer_wb / buffer_inv anywhere in the steady loop.
  auto gbar = [&](void) {
    __syncthreads();
    if (w == 0) {
      if (l == 0)
        A_STORE(flags + ((g << 5) + cs) * 4, ep);
      unsigned* f = flags + ((g << 5) + (l & 31)) * 4;
      int spins = 0;
      while (A_LOAD(f) < ep) {
        __builtin_amdgcn_s_sleep(1);
        if (++spins > SPIN_MAX) { *abflag = 1; break; }  // hang-proof escape
      }
    }
    __syncthreads();
    asm volatile("" ::: "memory");
    ep++;
  };

  __syncthreads();          // xbuf zeroing + abflag init complete
  if (!ch) xstage(0);       // x_0 -> xbuf[0]
  gbar();                   // h0 + staging visible group-wide
  if (*abflag) return;

  // step t: all waves MFMA over h_{t-1}; W1 waves finish y_{t-1}=MLP(h_{t-1});
  // gate waves add x_t + y-feedback, update c -> h_t. t==NL: final y only.
  for (int t = 0; t <= NL; ++t) {
    const _Float16* hr = hbuf + (size_t)(t & 1) * HBUF;

    // ---- phase 1: K=512 over h_{t-1}; A via relaxed (sc1) 8B loads from IC,
    // B from registers. 2 chunks x 8 k-steps => ~32 loads in flight.
    floatx4 acc[4][2] = {};
    const int growb = 64 * g + 32 * rh + c16;
    #pragma unroll
    for (int kc = 0; kc < 2; ++kc) {
      half8 ar[2][8];
      #pragma unroll
      for (int kk = 0; kk < 8; ++kk) {
        #pragma unroll
        for (int rt = 0; rt < 2; ++rt) {
          const _Float16* ap = hr + (size_t)((kc * 8 + kk) * 2 + (q >> 1)) * 8192
                               + (size_t)(growb + 16 * rt) * 16 + (q & 1) * 8;
          const unsigned long long* up = (const unsigned long long*)ap;
          union { unsigned long long u[2]; half8 h; } cv;
          cv.u[0] = A_LOAD(up);
          cv.u[1] = A_LOAD(up + 1);
          ar[rt][kk] = cv.h;
        }
      }
      #pragma unroll
      for (int kk = 0; kk < 8; ++kk)
        #pragma unroll
        for (int ct = 0; ct < 4; ++ct)
          #pragma unroll
          for (int rt = 0; rt < 2; ++rt)
            acc[ct][rt] = __builtin_amdgcn_mfma_f32_16x16x32_f16(
                ar[rt][kk], bfr[ct][kc * 8 + kk], acc[ct][rt], 0, 0, 0);
    }

    // ---- phase 2 (gate waves): x_t contribution, K=128 from LDS ----
    if (!ch && t < NL) {
      const _Float16* xb = XB + (size_t)(t & 1) * 64 * XB_STR;
      #pragma unroll
      for (int kb = 0; kb < 4; ++kb) {
        half8 ax[2];
        #pragma unroll
        for (int rt = 0; rt < 2; ++rt)
          ax[rt] = *(const half8*)(xb + (32 * rh + 16 * rt + c16) * XB_STR + kb * 32 + q * 8);
        #pragma unroll
        for (int ct = 0; ct < 4; ++ct) {
          half8 bf = *(const half8*)(B2s + (ct * 16 + c16) * B2_STR + kb * 32 + q * 8);
          #pragma unroll
          for (int rt = 0; rt < 2; ++rt)
            acc[ct][rt] = __builtin_amdgcn_mfma_f32_16x16x32_f16(ax[rt], bf, acc[ct][rt], 0, 0, 0);
        }
      }
      if (t + 1 < NL) xstage(t + 1);  // prefetch x_{t+1} into other LDS buffer
    }

    // ---- W1 waves: y_{t-1} (or pos init at t==0) ----
    if (ch) {
      if (t == 0) {
        if (l < 32) {
          int row = 32 * rh + l;
          const float* pp = pos + (size_t)(64 * g + row) * (NL * 2);
          ypres[row * 2 + 0] = pp[0];
          ypres[row * 2 + 1] = pp[1];
        }
      } else {
        // layer1 relu -> YST (f16); same-wave RAW, no block sync needed
        #pragma unroll
        for (int ct = 0; ct < 4; ++ct)
          #pragma unroll
          for (int rt = 0; rt < 2; ++rt)
            #pragma unroll
            for (int reg = 0; reg < 4; ++reg) {
              int row = 32 * rh + 16 * rt + q * 4 + reg;
              float v = acc[ct][rt][reg] + b1s[ct * 16 + c16];
              YST[row * YST_STR + ct * 16 + c16] = (_Float16)fmaxf(v, 0.f);
            }
        // layer2 via MFMA (16 outs, K=64)
        floatx4 a2c[2] = {};
        #pragma unroll
        for (int kk2 = 0; kk2 < 2; ++kk2)
          #pragma unroll
          for (int rt = 0; rt < 2; ++rt) {
            half8 af = *(const half8*)(YST + (32 * rh + 16 * rt + c16) * YST_STR + kk2 * 32 + q * 8);
            a2c[rt] = __builtin_amdgcn_mfma_f32_16x16x32_f16(af, w2f[kk2], a2c[rt], 0, 0, 0);
          }
        // relu2 -> Y2 (this region is re-used as HTX after the next sync)
        #pragma unroll
        for (int rt = 0; rt < 2; ++rt)
          #pragma unroll
          for (int reg = 0; reg < 4; ++reg) {
            int row = 32 * rh + 16 * rt + q * 4 + reg;
            float v = a2c[rt][reg] + b2s[c16];
            Y2[row * Y2_STR + c16] = (_Float16)fmaxf(v, 0.f);
          }
        // layer3 (2 outs, K=16) + relu -> ypres (+ global pos out by cs==0)
        if (l < 32) {
          int row = 32 * rh + l;
          float y0 = b3s[0], y1 = b3s[1];
          #pragma unroll
          for (int k = 0; k < 16; ++k) {
            float vv = (float)Y2[row * Y2_STR + k];
            y0 += vv * w3s[k];
            y1 += vv * w3s[16 + k];
          }
          y0 = fmaxf(y0, 0.f); y1 = fmaxf(y1, 0.f);
          ypres[row * 2 + 0] = y0;
          ypres[row * 2 + 1] = y1;
          if (cs == 0) {
            float2* op = (float2*)(out + (size_t)(64 * g + row) * (NL * 2) + (size_t)(t - 1) * 2);
            *op = make_float2(y0, y1);
          }
        }
      }
    }
    __syncthreads();  // ypres ready; Y2 use finished (HTX may now overwrite)

    // ---- gate epilogue: feedback + bias + LSTM cell; h_t -> LDS tile ----
    if (!ch && t < NL) {
      #pragma unroll
      for (int rt = 0; rt < 2; ++rt)
        #pragma unroll
        for (int reg = 0; reg < 4; ++reg) {
          int rl = 32 * rh + 16 * rt + q * 4 + reg;
          float yp0 = ypres[rl * 2], yp1 = ypres[rl * 2 + 1];
          float gi = acc[0][rt][reg] + bgs[c16]      + yp0 * wy0[c16]      + yp1 * wy1[c16];
          float gf = acc[1][rt][reg] + bgs[16 + c16] + yp0 * wy0[16 + c16] + yp1 * wy1[16 + c16];
          float gg = acc[2][rt][reg] + bgs[32 + c16] + yp0 * wy0[32 + c16] + yp1 * wy1[32 + c16];
          float go = acc[3][rt][reg] + bgs[48 + c16] + yp0 * wy0[48 + c16] + yp1 * wy1[48 + c16];
          float iv = fast_sigmoid(gi);
          float fv = fast_sigmoid(gf);
          float gv = fast_tanh(gg);
          float ov = fast_sigmoid(go);
          float cn = fv * cacc[rt][reg] + iv * gv;
          cacc[rt][reg] = cn;
          float hn = ov * fast_tanh(cn);
          HTX[rl * 16 + c16] = (_Float16)hn;   // LDS deposit for 8B-wide publish
          if (t == NL - 1) {
            out[(size_t)(NB * NL * 2) + (size_t)(64 * g + rl) * NH + cs * 16 + c16] = hn;
            out[(size_t)(NB * NL * 2) + (size_t)(NB * NH) + (size_t)(64 * g + rl) * NH + cs * 16 + c16] = cn;
          }
        }
    }

    if (t < NL) {
      __syncthreads();  // HTX tile complete
      // cooperative publish: 256 threads x 8B relaxed (sc1) stores -> IC
      {
        const int row = tid >> 2, cc = tid & 3;
        unsigned long long v = *(const unsigned long long*)(HTX + row * 16 + cc * 4);
        _Float16* hw = hbuf + (size_t)((t + 1) & 1) * HBUF;
        A_STORE((unsigned long long*)(hw + (size_t)cs * 8192
                                      + (size_t)(64 * g + row) * 16 + cc * 4), v);
      }
      gbar();               // syncthreads drains vmcnt -> stores at IC -> flag
      if (*abflag) return;  // barrier timed out somewhere: terminate cleanly
    }
  }
}

extern "C" void kernel_launch(void* const* d_in, const int* in_sizes, int n_in,
                              void* d_out, int out_size, void* d_ws, size_t ws_size,
                              hipStream_t stream) {
  (void)in_sizes; (void)n_in; (void)out_size; (void)ws_size;
  const float* x   = (const float*)d_in[0];
  const float* pos = (const float*)d_in[1];
  const float* h0  = (const float*)d_in[2];
  const float* c0  = (const float*)d_in[3];
  const float* Wih = (const float*)d_in[4];
  const float* Whh = (const float*)d_in[5];
  const float* bih = (const float*)d_in[6];
  const float* bhh = (const float*)d_in[7];
  const float* W1  = (const float*)d_in[8];
  const float* b1  = (const float*)d_in[9];
  const float* W2  = (const float*)d_in[10];
  const float* b2  = (const float*)d_in[11];
  const float* W3  = (const float*)d_in[12];
  const float* b3  = (const float*)d_in[13];
  float* out = (float*)d_out;

  hipMemsetAsync(d_ws, 0, 4096, stream);  // barrier flags

  void* args[] = { (void*)&x, (void*)&pos, (void*)&h0, (void*)&c0,
                   (void*)&Wih, (void*)&Whh, (void*)&bih, (void*)&bhh,
                   (void*)&W1, (void*)&b1, (void*)&W2, (void*)&b2,
                   (void*)&W3, (void*)&b3, (void*)&out, (void*)&d_ws };

  // Primary: cooperative launch (worked in R1/R4). Fallback: plain launch —
  // 256 blocks at 1 block/CU on 256 CUs are co-resident by capacity.
  hipError_t err = hipLaunchCooperativeKernel(
      reinterpret_cast<void*>(lstm_persist),
      dim3(256, 1, 1), dim3(256, 1, 1), args, (unsigned)SMEM_BYTES, stream);
  if (err != hipSuccess) {
    (void)hipGetLastError();  // clear sticky error
    lstm_persist<<<dim3(256, 1, 1), dim3(256, 1, 1), SMEM_BYTES, stream>>>(
        x, pos, h0, c0, Wih, Whh, bih, bhh, W1, b1, W2, b2, W3, b3, out, d_ws);
  }
}